// Round 9
// baseline (254.681 us; speedup 1.0000x reference)
//
#include <hip/hip_runtime.h>
#include <hip/hip_bf16.h>
#include <math.h>

#define Bn 16
#define Ln 512
#define Dn 1024
#define Pn 10

typedef short bf16x8 __attribute__((ext_vector_type(8)));
typedef float f32x4 __attribute__((ext_vector_type(4)));

// Split fp32 -> (hi, lo) bf16 bit-patterns. a ~= hi + lo to ~2^-17 rel.
__device__ __forceinline__ short2 bf16split(float x) {
    __hip_bfloat16 h = __float2bfloat16(x);
    float hf = __bfloat162float(h);
    __hip_bfloat16 l = __float2bfloat16(x - hf);
    short2 r;
    __builtin_memcpy(&r.x, &h, 2);
    __builtin_memcpy(&r.y, &l, 2);
    return r;
}

// ---------------------------------------------------------------------------
// Kernel 1: row L2 norms. Rows 0..8191 = sent1, 8192..16383 = sent2.
// ---------------------------------------------------------------------------
__global__ __launch_bounds__(256) void norms_kernel(const float* __restrict__ s1,
                                                    const float* __restrict__ s2,
                                                    float* __restrict__ nrm) {
    const int wave = threadIdx.x >> 6;
    const int lane = threadIdx.x & 63;
    const int row  = blockIdx.x * 4 + wave;
    const float* src = (row < Bn * Ln) ? (s1 + (size_t)row * Dn)
                                       : (s2 + (size_t)(row - Bn * Ln) * Dn);
    const float4* p4 = (const float4*)src;
    float acc = 0.f;
#pragma unroll
    for (int i = 0; i < 4; ++i) {
        float4 v = p4[lane + i * 64];
        acc = fmaf(v.x, v.x, acc);
        acc = fmaf(v.y, v.y, acc);
        acc = fmaf(v.z, v.z, acc);
        acc = fmaf(v.w, v.w, acc);
    }
#pragma unroll
    for (int m = 32; m; m >>= 1) acc += __shfl_xor(acc, m, 64);
    if (lane == 0) nrm[row] = sqrtf(acc);
}

// ---------------------------------------------------------------------------
// Kernel 2 (merged cvt+tr): s2 fp32 [B][L2][D] -> bf16 hi/lo in BOTH layouts:
// normal [B*L2][D] and transposed [B][D][L2]. One read of s2, 64x64 tiles.
// ---------------------------------------------------------------------------
__global__ __launch_bounds__(256) void prep_s2_kernel(const float* __restrict__ s2,
                                                      short* __restrict__ s2nh,
                                                      short* __restrict__ s2nl,
                                                      short* __restrict__ s2th,
                                                      short* __restrict__ s2tl) {
    __shared__ float tile[64][65];
    const int tid = threadIdx.x;
    const int tb  = blockIdx.x;          // 16 b * 8 l2tiles * 16 dtiles
    const int b   = tb >> 7;
    const int rem = tb & 127;
    const int l2c = (rem >> 4) * 64;
    const int dc  = (rem & 15) * 64;

#pragma unroll
    for (int i = 0; i < 4; ++i) {
        int r  = (tid >> 4) + 16 * i;
        int c4 = (tid & 15) * 4;
        float4 v = *(const float4*)(s2 + ((size_t)b * Ln + l2c + r) * Dn + dc + c4);
        tile[r][c4 + 0] = v.x;
        tile[r][c4 + 1] = v.y;
        tile[r][c4 + 2] = v.z;
        tile[r][c4 + 3] = v.w;
        short2 p0 = bf16split(v.x), p1 = bf16split(v.y),
               p2 = bf16split(v.z), p3 = bf16split(v.w);
        short4 h; h.x = p0.x; h.y = p1.x; h.z = p2.x; h.w = p3.x;
        short4 l; l.x = p0.y; l.y = p1.y; l.z = p2.y; l.w = p3.y;
        size_t noff = ((size_t)b * Ln + l2c + r) * Dn + dc + c4;
        *(short4*)(s2nh + noff) = h;
        *(short4*)(s2nl + noff) = l;
    }
    __syncthreads();
#pragma unroll
    for (int i = 0; i < 2; ++i) {
        int dr  = (tid >> 3) + 32 * i;
        int l2o = (tid & 7) * 8;
        bf16x8 hv, lv;
#pragma unroll
        for (int j = 0; j < 8; ++j) {
            short2 p = bf16split(tile[l2o + j][dr]);
            hv[j] = p.x;
            lv[j] = p.y;
        }
        size_t off = ((size_t)b * Dn + dc + dr) * Ln + l2c + l2o;
        *(bf16x8*)(s2th + off) = hv;
        *(bf16x8*)(s2tl + off) = lv;
    }
}

// ---------------------------------------------------------------------------
// Kernel 3: cos_kernel — block (b, 64-row l1 tile, l2-HALF).
// Computes S[64][256] = s1_tile @ s2_half^T (split-bf16 3-term MFMA, K=1024),
// converts to cos, writes cos bf16 hi/lo planes + per-half row sums.
// Wave tiling: 16 waves = 2 m-pairs x 8 col-pairs; each wave 2x2 MFMA tiles.
// Halved B-traffic vs round-7 (each block reads a HALF panel: 1 MB).
// ---------------------------------------------------------------------------
__global__ __launch_bounds__(1024) void cos_kernel(
        const float* __restrict__ s1, const float* __restrict__ nrm,
        const short* __restrict__ s2nh, const short* __restrict__ s2nl,
        short* __restrict__ cosH, short* __restrict__ cosL,
        float* __restrict__ sumP) {
    __shared__ float Sr[64][260];        // 66.6 KB
    __shared__ short Ah[2][64][72];      // 18.4 KB dbuf, 64-k slice
    __shared__ short Al[2][64][72];      // 18.4 KB
    __shared__ float n1c[64];
    __shared__ float n2c[256];
    __shared__ float red[64][16];

    const int tid  = threadIdx.x;
    const int w    = tid >> 6;
    const int lane = tid & 63;
    const int lr   = lane & 15;
    const int lg   = lane >> 4;
    const int p    = w >> 3;             // m-pair 0..1
    const int c    = w & 7;              // col-pair 0..7

    const int wg   = ((blockIdx.x & 7) << 5) | (blockIdx.x >> 3);  // XCD swizzle
    const int m8   = wg & 7;
    const int bh   = wg >> 3;
    const int half = bh & 1;
    const int b    = bh >> 1;
    const int R0   = m8 * 64;

    const float* s1b = s1 + ((size_t)b * Ln + R0) * Dn;   // [64][1024]
    const size_t s2row0 = (size_t)b * Ln + half * 256;    // row base in s2n

    if (tid < 64)  n1c[tid] = nrm[b * Ln + R0 + tid];
    if (tid < 256) n2c[tid] = nrm[Bn * Ln + b * Ln + half * 256 + tid];

    auto stageA = [&](int buf, int kb) {
        int r = tid >> 4, k4 = (tid & 15) * 4;
        float4 v = *(const float4*)(s1b + (size_t)r * Dn + kb + k4);
        short2 p0 = bf16split(v.x), p1 = bf16split(v.y),
               p2 = bf16split(v.z), p3 = bf16split(v.w);
        short4 h; h.x = p0.x; h.y = p1.x; h.z = p2.x; h.w = p3.x;
        short4 l; l.x = p0.y; l.y = p1.y; l.z = p2.y; l.w = p3.y;
        *(short4*)&Ah[buf][r][k4] = h;
        *(short4*)&Al[buf][r][k4] = l;
    };

    f32x4 acc[2][2];
#pragma unroll
    for (int pm = 0; pm < 2; ++pm)
#pragma unroll
        for (int tt = 0; tt < 2; ++tt) acc[pm][tt] = (f32x4){0.f, 0.f, 0.f, 0.f};

    stageA(0, 0);
    __syncthreads();

    for (int kb = 0; kb < Dn; kb += 64) {
        int cur = (kb >> 6) & 1;
        if (kb + 64 < Dn) stageA(cur ^ 1, kb + 64);
#pragma unroll
        for (int ks = 0; ks < 64; ks += 32) {
            bf16x8 ah[2], al[2];
#pragma unroll
            for (int pm = 0; pm < 2; ++pm) {
                int row = p * 32 + pm * 16 + lr;
                ah[pm] = *(const bf16x8*)&Ah[cur][row][ks + lg * 8];
                al[pm] = *(const bf16x8*)&Al[cur][row][ks + lg * 8];
            }
#pragma unroll
            for (int tt = 0; tt < 2; ++tt) {
                int l2 = (2 * c + tt) * 16 + lr;                 // local col
                size_t off = (s2row0 + l2) * Dn + kb + ks + lg * 8;
                bf16x8 bhv = *(const bf16x8*)(s2nh + off);
                bf16x8 blv = *(const bf16x8*)(s2nl + off);
#pragma unroll
                for (int pm = 0; pm < 2; ++pm) {
                    acc[pm][tt] = __builtin_amdgcn_mfma_f32_16x16x32_bf16(ah[pm], bhv, acc[pm][tt], 0, 0, 0);
                    acc[pm][tt] = __builtin_amdgcn_mfma_f32_16x16x32_bf16(ah[pm], blv, acc[pm][tt], 0, 0, 0);
                    acc[pm][tt] = __builtin_amdgcn_mfma_f32_16x16x32_bf16(al[pm], bhv, acc[pm][tt], 0, 0, 0);
                }
            }
        }
        __syncthreads();
    }
    // D layout: col = lane&15, row = (lane>>4)*4 + reg  [m89/m91, proven r5/r7]
#pragma unroll
    for (int pm = 0; pm < 2; ++pm)
#pragma unroll
        for (int tt = 0; tt < 2; ++tt)
#pragma unroll
            for (int reg = 0; reg < 4; ++reg)
                Sr[p * 32 + pm * 16 + lg * 4 + reg][(2 * c + tt) * 16 + lr] = acc[pm][tt][reg];
    __syncthreads();

    // cos conversion + split-write + row sums (per half)
    {
        int r = tid >> 4, part = tid & 15;
        float n1v = n1c[r];
        short* cH = cosH + ((size_t)b * Ln + R0 + r) * Ln + half * 256;
        short* cL = cosL + ((size_t)b * Ln + R0 + r) * Ln + half * 256;
        float s = 0.f;
#pragma unroll 4
        for (int j = 0; j < 16; ++j) {
            int l2 = part + 16 * j;
            float d = Sr[r][l2];
            float cv = d / fmaxf(n1v * n2c[l2], 1e-8f);
            short2 sp = bf16split(cv);
            cH[l2] = sp.x;
            cL[l2] = sp.y;
            s += cv;
        }
        red[r][part] = s;
    }
    __syncthreads();
    if (tid < 64) {
        float s = 0.f;
#pragma unroll
        for (int j = 0; j < 16; ++j) s += red[tid][j];
        sumP[((size_t)b * Ln + R0 + tid) * 2 + half] = s;
    }
}

// ---------------------------------------------------------------------------
// Kernel 4: fold_kernel — block (b, 64-row l1 tile, d-HALF).
// ws = cos @ s2 over K=l2=512; folds into ss=sum ws^2, sd=sum s1*ws partials
// per (row, d-half). A = pre-split cos planes staged via LDS (no VALU split),
// B = transposed s2 planes direct global->reg (HALF panel: 1 MB per block).
// Wave tiling: 2 m-pairs x 8 groups x 4 d-tiles.
// ---------------------------------------------------------------------------
__global__ __launch_bounds__(1024) void fold_kernel(
        const float* __restrict__ s1,
        const short* __restrict__ s2th, const short* __restrict__ s2tl,
        const short* __restrict__ cosH, const short* __restrict__ cosL,
        float* __restrict__ ssP, float* __restrict__ sdP) {
    __shared__ short ChH[2][64][72];     // 18.4 KB dbuf, 64-l2 slice of cos hi
    __shared__ short ChL[2][64][72];     // 18.4 KB lo
    __shared__ float redS[64][8];
    __shared__ float redD[64][8];

    const int tid  = threadIdx.x;
    const int w    = tid >> 6;
    const int lane = tid & 63;
    const int lr   = lane & 15;
    const int lg   = lane >> 4;
    const int p    = w >> 3;             // m-pair 0..1
    const int c    = w & 7;              // d-group 0..7 (4 tiles each)

    const int wg   = ((blockIdx.x & 7) << 5) | (blockIdx.x >> 3);  // XCD swizzle
    const int m8   = wg & 7;
    const int bh   = wg >> 3;
    const int dh   = bh & 1;
    const int b    = bh >> 1;
    const int R0   = m8 * 64;

    const float* s1b = s1 + ((size_t)b * Ln + R0) * Dn;
    const size_t cosrow0 = (size_t)b * Ln + R0;           // row base in cos
    const size_t s2trow0 = (size_t)b * Dn + dh * 512;     // row base in s2t

    auto stageC = [&](int buf, int kc) {
        int r = tid >> 4, q4 = (tid & 15) * 4;
        *(short4*)&ChH[buf][r][q4] = *(const short4*)(cosH + (cosrow0 + r) * Ln + kc + q4);
        *(short4*)&ChL[buf][r][q4] = *(const short4*)(cosL + (cosrow0 + r) * Ln + kc + q4);
    };

    f32x4 acc[2][4];
#pragma unroll
    for (int pm = 0; pm < 2; ++pm)
#pragma unroll
        for (int j = 0; j < 4; ++j) acc[pm][j] = (f32x4){0.f, 0.f, 0.f, 0.f};

    stageC(0, 0);
    __syncthreads();

    for (int kc = 0; kc < Ln; kc += 64) {
        int cur = (kc >> 6) & 1;
        if (kc + 64 < Ln) stageC(cur ^ 1, kc + 64);
#pragma unroll
        for (int ks = 0; ks < 64; ks += 32) {
            bf16x8 ah[2], al[2];
#pragma unroll
            for (int pm = 0; pm < 2; ++pm) {
                int row = p * 32 + pm * 16 + lr;
                ah[pm] = *(const bf16x8*)&ChH[cur][row][ks + lg * 8];
                al[pm] = *(const bf16x8*)&ChL[cur][row][ks + lg * 8];
            }
#pragma unroll
            for (int j = 0; j < 4; ++j) {
                int d = (c * 4 + j) * 16 + lr;                    // local d
                size_t off = (s2trow0 + d) * Ln + kc + ks + lg * 8;
                bf16x8 bhv = *(const bf16x8*)(s2th + off);
                bf16x8 blv = *(const bf16x8*)(s2tl + off);
#pragma unroll
                for (int pm = 0; pm < 2; ++pm) {
                    acc[pm][j] = __builtin_amdgcn_mfma_f32_16x16x32_bf16(ah[pm], bhv, acc[pm][j], 0, 0, 0);
                    acc[pm][j] = __builtin_amdgcn_mfma_f32_16x16x32_bf16(ah[pm], blv, acc[pm][j], 0, 0, 0);
                    acc[pm][j] = __builtin_amdgcn_mfma_f32_16x16x32_bf16(al[pm], bhv, acc[pm][j], 0, 0, 0);
                }
            }
        }
        __syncthreads();
    }

    // fold ws into ss/sd
    float ss[2][4], sd[2][4];
#pragma unroll
    for (int pm = 0; pm < 2; ++pm)
#pragma unroll
        for (int reg = 0; reg < 4; ++reg) { ss[pm][reg] = 0.f; sd[pm][reg] = 0.f; }

#pragma unroll
    for (int pm = 0; pm < 2; ++pm)
#pragma unroll
        for (int j = 0; j < 4; ++j) {
            int d = dh * 512 + (c * 4 + j) * 16 + lr;
#pragma unroll
            for (int reg = 0; reg < 4; ++reg) {
                int row = p * 32 + pm * 16 + lg * 4 + reg;
                float wv = acc[pm][j][reg];
                ss[pm][reg] = fmaf(wv, wv, ss[pm][reg]);
                float x = s1b[(size_t)row * Dn + d];
                sd[pm][reg] = fmaf(x, wv, sd[pm][reg]);
            }
        }
#pragma unroll
    for (int pm = 0; pm < 2; ++pm)
#pragma unroll
        for (int reg = 0; reg < 4; ++reg) {
#pragma unroll
            for (int msk = 8; msk; msk >>= 1) {
                ss[pm][reg] += __shfl_xor(ss[pm][reg], msk, 64);
                sd[pm][reg] += __shfl_xor(sd[pm][reg], msk, 64);
            }
        }
    if (lr == 0) {
#pragma unroll
        for (int pm = 0; pm < 2; ++pm)
#pragma unroll
            for (int reg = 0; reg < 4; ++reg) {
                int row = p * 32 + pm * 16 + lg * 4 + reg;
                redS[row][c] = ss[pm][reg];
                redD[row][c] = sd[pm][reg];
            }
    }
    __syncthreads();

    if (tid < 64) {
        float sS = 0.f, sD = 0.f;
#pragma unroll
        for (int j = 0; j < 8; ++j) { sS += redS[tid][j]; sD += redD[tid][j]; }
        size_t o = ((size_t)b * Ln + R0 + tid) * 2 + dh;
        ssP[o] = sS;
        sdP[o] = sD;
    }
}

// ---------------------------------------------------------------------------
// Kernel 5: epilogue — combine halves + multi-perspective cosine.
// ---------------------------------------------------------------------------
__global__ __launch_bounds__(256) void epi_kernel(
        const float* __restrict__ nrm, const float* __restrict__ kern,
        const float* __restrict__ sumP, const float* __restrict__ ssP,
        const float* __restrict__ sdP, float* __restrict__ out) {
    int idx = blockIdx.x * 256 + threadIdx.x;   // 8192 rows x 16 slots
    int r = idx >> 4, pp = idx & 15;
    if (pp >= Pn) return;
    float ssT = ssP[r * 2] + ssP[r * 2 + 1];
    float sdT = sdP[r * 2] + sdP[r * 2 + 1];
    float scv = sumP[r * 2] + sumP[r * 2 + 1] + 1e-8f;
    float n1v = nrm[r];
    float kp  = kern[pp];
    float kp2 = kp * kp;
    float wsn = sqrtf(ssT);
    float dot2  = kp2 * sdT / scv;
    float denom = fmaxf(kp2 * n1v * wsn / fabsf(scv), 1e-8f);
    out[(size_t)r * Pn + pp] = dot2 / denom;
}

// ===========================================================================
// Mid-fallback: round-7 fused kernel (proven, 135 us) if ws too small for the
// K-split buffers.
// ===========================================================================
__global__ __launch_bounds__(1024, 4) void mfma_fused_kernel(
        const float* __restrict__ s1,
        const float* __restrict__ kern, const float* __restrict__ nrm,
        const short* __restrict__ s2nh, const short* __restrict__ s2nl,
        const short* __restrict__ s2th, const short* __restrict__ s2tl,
        float* __restrict__ out) {
    __shared__ float Sr[32][516];
    __shared__ short Ah[2][32][136];
    __shared__ short Al[2][32][136];
    __shared__ float n2c[Ln];
    __shared__ float n1c[32];
    __shared__ float scl[32];
    __shared__ float red[32][32];
    __shared__ float redS[32][16];
    __shared__ float redD[32][16];
    __shared__ float kc_[16];

    const int tid  = threadIdx.x;
    const int w    = tid >> 6;
    const int lane = tid & 63;
    const int lr   = lane & 15;
    const int lg   = lane >> 4;

    const int wg = ((blockIdx.x & 7) << 5) | (blockIdx.x >> 3);
    const int b  = wg >> 4;
    const int R0 = (wg & 15) * 32;

    const float* s1b = s1 + ((size_t)b * Ln + R0) * Dn;
    const size_t s2row0  = (size_t)b * Ln;
    const size_t s2trow0 = (size_t)b * Dn;

    if (tid < 32) n1c[tid] = nrm[b * Ln + R0 + tid];
    if (tid < Ln) n2c[tid] = nrm[Bn * Ln + b * Ln + tid];
    if (tid < Pn) kc_[tid] = kern[tid];

    auto stageA = [&](int buf, int kb) {
        int r = tid >> 5, k = (tid & 31) * 4;
        float4 v = *(const float4*)(s1b + (size_t)r * Dn + kb + k);
        short2 p0 = bf16split(v.x), p1 = bf16split(v.y),
               p2 = bf16split(v.z), p3 = bf16split(v.w);
        short4 h; h.x = p0.x; h.y = p1.x; h.z = p2.x; h.w = p3.x;
        short4 l; l.x = p0.y; l.y = p1.y; l.z = p2.y; l.w = p3.y;
        *(short4*)&Ah[buf][r][k] = h;
        *(short4*)&Al[buf][r][k] = l;
    };

    f32x4 accA[2][2];
#pragma unroll
    for (int m = 0; m < 2; ++m)
#pragma unroll
        for (int t = 0; t < 2; ++t) accA[m][t] = (f32x4){0.f, 0.f, 0.f, 0.f};

    stageA(0, 0);
    __syncthreads();

    for (int kb = 0; kb < Dn; kb += 128) {
        int cur = (kb >> 7) & 1;
        if (kb + 128 < Dn) stageA(cur ^ 1, kb + 128);
#pragma unroll
        for (int ks = 0; ks < 128; ks += 32) {
            bf16x8 ah[2], al[2];
#pragma unroll
            for (int m = 0; m < 2; ++m) {
                ah[m] = *(const bf16x8*)&Ah[cur][m * 16 + lr][ks + lg * 8];
                al[m] = *(const bf16x8*)&Al[cur][m * 16 + lr][ks + lg * 8];
            }
#pragma unroll
            for (int t = 0; t < 2; ++t) {
                int l2 = (w * 2 + t) * 16 + lr;
                size_t off = (s2row0 + l2) * Dn + kb + ks + lg * 8;
                bf16x8 bh = *(const bf16x8*)(s2nh + off);
                bf16x8 bl = *(const bf16x8*)(s2nl + off);
#pragma unroll
                for (int m = 0; m < 2; ++m) {
                    accA[m][t] = __builtin_amdgcn_mfma_f32_16x16x32_bf16(ah[m], bh, accA[m][t], 0, 0, 0);
                    accA[m][t] = __builtin_amdgcn_mfma_f32_16x16x32_bf16(ah[m], bl, accA[m][t], 0, 0, 0);
                    accA[m][t] = __builtin_amdgcn_mfma_f32_16x16x32_bf16(al[m], bh, accA[m][t], 0, 0, 0);
                }
            }
        }
        __syncthreads();
    }
#pragma unroll
    for (int m = 0; m < 2; ++m)
#pragma unroll
        for (int t = 0; t < 2; ++t)
#pragma unroll
            for (int reg = 0; reg < 4; ++reg)
                Sr[m * 16 + lg * 4 + reg][(w * 2 + t) * 16 + lr] = accA[m][t][reg];
    __syncthreads();

    {
        int r = tid >> 5, part = tid & 31;
        float n1v = n1c[r];
        float s = 0.f;
#pragma unroll 8
        for (int j = 0; j < 16; ++j) {
            int l2 = part + 32 * j;
            float d = Sr[r][l2];
            float cv = d / fmaxf(n1v * n2c[l2], 1e-8f);
            Sr[r][l2] = cv;
            s += cv;
        }
        red[r][part] = s;
    }
    __syncthreads();
    if (tid < 32) {
        float s = 0.f;
#pragma unroll
        for (int j = 0; j < 32; ++j) s += red[tid][j];
        scl[tid] = s + 1e-8f;
    }
    __syncthreads();

    f32x4 accB[2][4];
#pragma unroll
    for (int m = 0; m < 2; ++m)
#pragma unroll
        for (int t = 0; t < 4; ++t) accB[m][t] = (f32x4){0.f, 0.f, 0.f, 0.f};

    for (int kc = 0; kc < Ln; kc += 32) {
        bf16x8 ah[2], al[2];
#pragma unroll
        for (int m = 0; m < 2; ++m) {
            const float* ap = &Sr[m * 16 + lr][kc + lg * 8];
            float4 v0 = *(const float4*)ap;
            float4 v1 = *(const float4*)(ap + 4);
            float f[8] = {v0.x, v0.y, v0.z, v0.w, v1.x, v1.y, v1.z, v1.w};
#pragma unroll
            for (int j = 0; j < 8; ++j) {
                short2 pz = bf16split(f[j]);
                ah[m][j] = pz.x;
                al[m][j] = pz.y;
            }
        }
#pragma unroll
        for (int t = 0; t < 4; ++t) {
            int d = (w * 4 + t) * 16 + lr;
            size_t off = (s2trow0 + d) * Ln + kc + lg * 8;
            bf16x8 bh = *(const bf16x8*)(s2th + off);
            bf16x8 bl = *(const bf16x8*)(s2tl + off);
#pragma unroll
            for (int m = 0; m < 2; ++m) {
                accB[m][t] = __builtin_amdgcn_mfma_f32_16x16x32_bf16(ah[m], bh, accB[m][t], 0, 0, 0);
                accB[m][t] = __builtin_amdgcn_mfma_f32_16x16x32_bf16(ah[m], bl, accB[m][t], 0, 0, 0);
                accB[m][t] = __builtin_amdgcn_mfma_f32_16x16x32_bf16(al[m], bh, accB[m][t], 0, 0, 0);
            }
        }
    }

    float ss[2][4], sd[2][4];
#pragma unroll
    for (int m = 0; m < 2; ++m)
#pragma unroll
        for (int reg = 0; reg < 4; ++reg) { ss[m][reg] = 0.f; sd[m][reg] = 0.f; }

#pragma unroll
    for (int m = 0; m < 2; ++m)
#pragma unroll
        for (int t = 0; t < 4; ++t) {
            int d = (w * 4 + t) * 16 + lr;
#pragma unroll
            for (int reg = 0; reg < 4; ++reg) {
                int row = m * 16 + lg * 4 + reg;
                float wv = accB[m][t][reg];
                ss[m][reg] = fmaf(wv, wv, ss[m][reg]);
                float x = s1b[(size_t)row * Dn + d];
                sd[m][reg] = fmaf(x, wv, sd[m][reg]);
            }
        }
#pragma unroll
    for (int m = 0; m < 2; ++m)
#pragma unroll
        for (int reg = 0; reg < 4; ++reg) {
#pragma unroll
            for (int msk = 8; msk; msk >>= 1) {
                ss[m][reg] += __shfl_xor(ss[m][reg], msk, 64);
                sd[m][reg] += __shfl_xor(sd[m][reg], msk, 64);
            }
        }
    if (lr == 0) {
#pragma unroll
        for (int m = 0; m < 2; ++m)
#pragma unroll
            for (int reg = 0; reg < 4; ++reg) {
                redS[m * 16 + lg * 4 + reg][w] = ss[m][reg];
                redD[m * 16 + lg * 4 + reg][w] = sd[m][reg];
            }
    }
    __syncthreads();

    if (tid < 32 * Pn) {
        int r = tid / Pn, pq = tid % Pn;
        float ssT = 0.f, sdT = 0.f;
#pragma unroll
        for (int j = 0; j < 16; ++j) { ssT += redS[r][j]; sdT += redD[r][j]; }
        float n1v = n1c[r];
        float scv = scl[r];
        float kp  = kc_[pq];
        float kp2 = kp * kp;
        float wsn = sqrtf(ssT);
        float dot2  = kp2 * sdT / scv;
        float denom = fmaxf(kp2 * n1v * wsn / fabsf(scv), 1e-8f);
        out[(size_t)(b * Ln + R0 + r) * Pn + pq] = dot2 / denom;
    }
}

extern "C" void kernel_launch(void* const* d_in, const int* in_sizes, int n_in,
                              void* d_out, int out_size, void* d_ws, size_t ws_size,
                              hipStream_t stream) {
    const float* s1   = (const float*)d_in[0];
    const float* s2   = (const float*)d_in[1];
    const float* kern = (const float*)d_in[2];
    float* out = (float*)d_out;

    char* w = (char*)d_ws;
    float* nrm = (float*)w;                               // 64 KB
    const size_t SZ1 = (size_t)Bn * Ln * Dn * sizeof(short);  // 16 MB
    const size_t SZC = (size_t)Bn * Ln * Ln * sizeof(short);  // 8 MB
    const size_t SZP = (size_t)Bn * Ln * 2 * sizeof(float);   // 64 KB
    short* s2nh = (short*)(w + 65536);
    short* s2nl = (short*)(w + 65536 + SZ1);
    short* s2th = (short*)(w + 65536 + 2 * SZ1);
    short* s2tl = (short*)(w + 65536 + 3 * SZ1);
    short* cosH = (short*)(w + 65536 + 4 * SZ1);
    short* cosL = (short*)(w + 65536 + 4 * SZ1 + SZC);
    float* sumP = (float*)(w + 65536 + 4 * SZ1 + 2 * SZC);
    float* ssP  = (float*)(w + 65536 + 4 * SZ1 + 2 * SZC + SZP);
    float* sdP  = (float*)(w + 65536 + 4 * SZ1 + 2 * SZC + 2 * SZP);
    const size_t NEED1 = 65536 + 4 * SZ1;                      // ~64.1 MB
    const size_t NEED2 = 65536 + 4 * SZ1 + 2 * SZC + 3 * SZP;  // ~81.1 MB

    hipLaunchKernelGGL(norms_kernel, dim3((Bn * Ln * 2) / 4), dim3(256), 0, stream,
                       s1, s2, nrm);

    if (ws_size >= NEED2) {
        // K-split MFMA path (halved panel traffic)
        hipLaunchKernelGGL(prep_s2_kernel, dim3(Bn * 8 * 16), dim3(256), 0, stream,
                           s2, s2nh, s2nl, s2th, s2tl);
        hipLaunchKernelGGL(cos_kernel, dim3(256), dim3(1024), 0, stream,
                           s1, nrm, s2nh, s2nl, cosH, cosL, sumP);
        hipLaunchKernelGGL(fold_kernel, dim3(256), dim3(1024), 0, stream,
                           s1, s2th, s2tl, cosH, cosL, ssP, sdP);
        hipLaunchKernelGGL(epi_kernel, dim3(Bn * Ln * 16 / 256), dim3(256), 0, stream,
                           nrm, kern, sumP, ssP, sdP, out);
    } else if (ws_size >= NEED1) {
        // round-7 fused path (proven 135 us)
        hipLaunchKernelGGL(prep_s2_kernel, dim3(Bn * 8 * 16), dim3(256), 0, stream,
                           s2, s2nh, s2nl, s2th, s2tl);
        hipLaunchKernelGGL(mfma_fused_kernel, dim3(Bn * (Ln / 32)), dim3(1024), 0, stream,
                           s1, kern, nrm, s2nh, s2nl, s2th, s2tl, out);
    }
}

// Round 10
// 186.693 us; speedup vs baseline: 1.3642x; 1.3642x over previous
//
#include <hip/hip_runtime.h>
#include <hip/hip_bf16.h>
#include <math.h>

#define Bn 16
#define Ln 512
#define Dn 1024
#define Pn 10

typedef short bf16x8 __attribute__((ext_vector_type(8)));
typedef float f32x4 __attribute__((ext_vector_type(4)));

// Split fp32 -> (hi, lo) bf16 bit-patterns. a ~= hi + lo to ~2^-17 rel.
__device__ __forceinline__ short2 bf16split(float x) {
    __hip_bfloat16 h = __float2bfloat16(x);
    float hf = __bfloat162float(h);
    __hip_bfloat16 l = __float2bfloat16(x - hf);
    short2 r;
    __builtin_memcpy(&r.x, &h, 2);
    __builtin_memcpy(&r.y, &l, 2);
    return r;
}

// Async 16B/lane global->LDS. LDS dest = wave-uniform base + lane*16.
__device__ __forceinline__ void load_lds16(const short* g, short* l) {
    __builtin_amdgcn_global_load_lds(
        (const __attribute__((address_space(1))) unsigned int*)g,
        (__attribute__((address_space(3))) unsigned int*)l, 16, 0, 0);
}

// XOR swizzle of 16B granule index within a 128B row (kills 16-way conflicts)
#define SWZ(row, kg) ((kg) ^ ((row) & 7))

// ---------------------------------------------------------------------------
// Kernel 1: row L2 norms. Rows 0..8191 = sent1, 8192..16383 = sent2.
// ---------------------------------------------------------------------------
__global__ __launch_bounds__(256) void norms_kernel(const float* __restrict__ s1,
                                                    const float* __restrict__ s2,
                                                    float* __restrict__ nrm) {
    const int wave = threadIdx.x >> 6;
    const int lane = threadIdx.x & 63;
    const int row  = blockIdx.x * 4 + wave;
    const float* src = (row < Bn * Ln) ? (s1 + (size_t)row * Dn)
                                       : (s2 + (size_t)(row - Bn * Ln) * Dn);
    const float4* p4 = (const float4*)src;
    float acc = 0.f;
#pragma unroll
    for (int i = 0; i < 4; ++i) {
        float4 v = p4[lane + i * 64];
        acc = fmaf(v.x, v.x, acc);
        acc = fmaf(v.y, v.y, acc);
        acc = fmaf(v.z, v.z, acc);
        acc = fmaf(v.w, v.w, acc);
    }
#pragma unroll
    for (int m = 32; m; m >>= 1) acc += __shfl_xor(acc, m, 64);
    if (lane == 0) nrm[row] = sqrtf(acc);
}

// ---------------------------------------------------------------------------
// Kernel 2: s2 fp32 [B][L2][D] -> bf16 hi/lo in BOTH layouts.
// ---------------------------------------------------------------------------
__global__ __launch_bounds__(256) void prep_s2_kernel(const float* __restrict__ s2,
                                                      short* __restrict__ s2nh,
                                                      short* __restrict__ s2nl,
                                                      short* __restrict__ s2th,
                                                      short* __restrict__ s2tl) {
    __shared__ float tile[64][65];
    const int tid = threadIdx.x;
    const int tb  = blockIdx.x;          // 16 b * 8 l2tiles * 16 dtiles
    const int b   = tb >> 7;
    const int rem = tb & 127;
    const int l2c = (rem >> 4) * 64;
    const int dc  = (rem & 15) * 64;

#pragma unroll
    for (int i = 0; i < 4; ++i) {
        int r  = (tid >> 4) + 16 * i;
        int c4 = (tid & 15) * 4;
        float4 v = *(const float4*)(s2 + ((size_t)b * Ln + l2c + r) * Dn + dc + c4);
        tile[r][c4 + 0] = v.x;
        tile[r][c4 + 1] = v.y;
        tile[r][c4 + 2] = v.z;
        tile[r][c4 + 3] = v.w;
        short2 p0 = bf16split(v.x), p1 = bf16split(v.y),
               p2 = bf16split(v.z), p3 = bf16split(v.w);
        short4 h; h.x = p0.x; h.y = p1.x; h.z = p2.x; h.w = p3.x;
        short4 l; l.x = p0.y; l.y = p1.y; l.z = p2.y; l.w = p3.y;
        size_t noff = ((size_t)b * Ln + l2c + r) * Dn + dc + c4;
        *(short4*)(s2nh + noff) = h;
        *(short4*)(s2nl + noff) = l;
    }
    __syncthreads();
#pragma unroll
    for (int i = 0; i < 2; ++i) {
        int dr  = (tid >> 3) + 32 * i;
        int l2o = (tid & 7) * 8;
        bf16x8 hv, lv;
#pragma unroll
        for (int j = 0; j < 8; ++j) {
            short2 p = bf16split(tile[l2o + j][dr]);
            hv[j] = p.x;
            lv[j] = p.y;
        }
        size_t off = ((size_t)b * Dn + dc + dr) * Ln + l2c + l2o;
        *(bf16x8*)(s2th + off) = hv;
        *(bf16x8*)(s2tl + off) = lv;
    }
}

// ---------------------------------------------------------------------------
// Kernel 3 v2: cos2 — 64x128 output tile per block, grid 512 (16b x 8m x 4q),
// 1024 thr = 16 waves (wr=w>>2, wc=w&3; per wave 16 rows x 32 cols).
// A (s1) VALU-split staged to LDS, double-buffered, K-window 64.
// B (pre-split s2n) staged via async global_load_lds with m201 both-sides
// swizzle: linear LDS dest, inverse-swizzled per-lane global source,
// swizzled ds_read_b128. cos conversion IN REGISTERS (no Sr buffer).
// ---------------------------------------------------------------------------
__global__ __launch_bounds__(1024) void cos2_kernel(
        const float* __restrict__ s1, const float* __restrict__ nrm,
        const short* __restrict__ s2nh, const short* __restrict__ s2nl,
        short* __restrict__ cosH, short* __restrict__ cosL,
        float* __restrict__ sumP) {
    __shared__ short Ah[2][64][72];      // 18 KB  (VALU-split A, padded)
    __shared__ short Al[2][64][72];      // 18 KB
    __shared__ short Bh[2][128 * 64];    // 32 KB  (linear, swizzled granules)
    __shared__ short Bl[2][128 * 64];    // 32 KB
    __shared__ float n1c[64];
    __shared__ float n2c[128];
    __shared__ float red[64][4];

    const int tid  = threadIdx.x;
    const int w    = tid >> 6;           // wave 0..15
    const int lane = tid & 63;
    const int lr   = lane & 15;
    const int lg   = lane >> 4;
    const int wr   = w >> 2;             // row-tile 0..3 (16 rows each)
    const int wc   = w & 3;              // col-group 0..3 (32 cols each)

    const int wg = ((blockIdx.x & 7) << 6) | (blockIdx.x >> 3);  // 512 = 8x64
    const int q  = wg & 3;               // col quarter (128 cols)
    const int m8 = (wg >> 2) & 7;        // 64-row tile
    const int b  = wg >> 5;
    const int R0 = m8 * 64;

    const float* s1b = s1 + ((size_t)b * Ln + R0) * Dn;

    if (tid < 64)  n1c[tid] = nrm[b * Ln + R0 + tid];
    if (tid < 128) n2c[tid] = nrm[Bn * Ln + b * Ln + q * 128 + tid];

    auto stageA = [&](int buf, int kb) {
        int r = tid >> 4, k4 = (tid & 15) * 4;
        float4 v = *(const float4*)(s1b + (size_t)r * Dn + kb + k4);
        short2 p0 = bf16split(v.x), p1 = bf16split(v.y),
               p2 = bf16split(v.z), p3 = bf16split(v.w);
        short4 h; h.x = p0.x; h.y = p1.x; h.z = p2.x; h.w = p3.x;
        short4 l; l.x = p0.y; l.y = p1.y; l.z = p2.y; l.w = p3.y;
        *(short4*)&Ah[buf][r][k4] = h;
        *(short4*)&Al[buf][r][k4] = l;
    };
    auto stageB = [&](int buf, int kb) {
        // wave w stages rows [w*8, w*8+8) of the 128-col slice, 8 granules each
        int localrow = w * 8 + (lane >> 3);
        int gd = (lane & 7) ^ (localrow & 7);          // inverse swizzle on src
        size_t src = ((size_t)(b * Ln + q * 128 + localrow)) * Dn + kb + gd * 8;
        load_lds16(s2nh + src, &Bh[buf][w * 512]);
        load_lds16(s2nl + src, &Bl[buf][w * 512]);
    };

    f32x4 acc[2];
    acc[0] = (f32x4){0.f, 0.f, 0.f, 0.f};
    acc[1] = (f32x4){0.f, 0.f, 0.f, 0.f};

    stageA(0, 0);
    stageB(0, 0);
    __syncthreads();

    for (int kb = 0; kb < Dn; kb += 64) {
        int buf = (kb >> 6) & 1;
        if (kb + 64 < Dn) { stageA(buf ^ 1, kb + 64); stageB(buf ^ 1, kb + 64); }
#pragma unroll
        for (int ks = 0; ks < 64; ks += 32) {
            bf16x8 ah = *(const bf16x8*)&Ah[buf][wr * 16 + lr][ks + lg * 8];
            bf16x8 al = *(const bf16x8*)&Al[buf][wr * 16 + lr][ks + lg * 8];
            int kg = (ks >> 3) + lg;
#pragma unroll
            for (int t = 0; t < 2; ++t) {
                int rowB = wc * 32 + t * 16 + lr;
                int off = rowB * 64 + SWZ(rowB, kg) * 8;   // swizzled read
                bf16x8 bh = *(const bf16x8*)&Bh[buf][off];
                bf16x8 bl = *(const bf16x8*)&Bl[buf][off];
                acc[t] = __builtin_amdgcn_mfma_f32_16x16x32_bf16(ah, bh, acc[t], 0, 0, 0);
                acc[t] = __builtin_amdgcn_mfma_f32_16x16x32_bf16(ah, bl, acc[t], 0, 0, 0);
                acc[t] = __builtin_amdgcn_mfma_f32_16x16x32_bf16(al, bh, acc[t], 0, 0, 0);
            }
        }
        __syncthreads();
    }

    // cos conversion in registers + split write + row-sum partials
    // D layout: col = lane&15, row = lg*4 + reg  [m89/m91, proven r5/r7/r9]
#pragma unroll
    for (int reg = 0; reg < 4; ++reg) {
        int rloc = wr * 16 + lg * 4 + reg;
        float n1v = n1c[rloc];
        float s = 0.f;
#pragma unroll
        for (int t = 0; t < 2; ++t) {
            int cloc = wc * 32 + t * 16 + lr;
            float cv = acc[t][reg] / fmaxf(n1v * n2c[cloc], 1e-8f);
            s += cv;
            short2 sp = bf16split(cv);
            size_t o = ((size_t)(b * Ln + R0 + rloc)) * Ln + q * 128 + cloc;
            cosH[o] = sp.x;
            cosL[o] = sp.y;
        }
        s += __shfl_xor(s, 1, 64);
        s += __shfl_xor(s, 2, 64);
        s += __shfl_xor(s, 4, 64);
        s += __shfl_xor(s, 8, 64);
        if (lr == 0) red[rloc][wc] = s;
    }
    __syncthreads();
    if (tid < 64) {
        float s = red[tid][0] + red[tid][1] + red[tid][2] + red[tid][3];
        sumP[((size_t)(b * Ln + R0 + tid)) * 4 + q] = s;
    }
}

// ---------------------------------------------------------------------------
// Kernel 4 v2: fold2 — 64 rows x 128 d-cols per block, grid 1024 (16bx8mx8dq),
// 1024 thr. BOTH operands staged via async global_load_lds + swizzle:
// A = pre-split cos planes, B = pre-split transposed s2 planes. K = l2 = 512.
// ws folded into ss/sd partials per (row, dq).
// ---------------------------------------------------------------------------
__global__ __launch_bounds__(1024) void fold2_kernel(
        const float* __restrict__ s1,
        const short* __restrict__ s2th, const short* __restrict__ s2tl,
        const short* __restrict__ cosH, const short* __restrict__ cosL,
        float* __restrict__ ssP, float* __restrict__ sdP) {
    __shared__ short Ah[2][64 * 64];     // 16 KB (linear swizzled)
    __shared__ short Al[2][64 * 64];     // 16 KB
    __shared__ short Bh[2][128 * 64];    // 32 KB
    __shared__ short Bl[2][128 * 64];    // 32 KB
    __shared__ float redS[64][4];
    __shared__ float redD[64][4];

    const int tid  = threadIdx.x;
    const int w    = tid >> 6;
    const int lane = tid & 63;
    const int lr   = lane & 15;
    const int lg   = lane >> 4;
    const int wr   = w >> 2;
    const int wc   = w & 3;

    const int wg = ((blockIdx.x & 7) << 7) | (blockIdx.x >> 3);  // 1024 = 8x128
    const int dq = wg & 7;               // d eighth (128 cols)
    const int m8 = (wg >> 3) & 7;
    const int b  = wg >> 6;
    const int R0 = m8 * 64;

    const float* s1b = s1 + ((size_t)b * Ln + R0) * Dn;

    auto stage = [&](int buf, int kc) {
        {   // A: waves 0..7 -> hi plane, 8..15 -> lo plane; rows (w&7)*8..+8
            int wa = w & 7;
            int localrow = wa * 8 + (lane >> 3);
            int gd = (lane & 7) ^ (localrow & 7);
            size_t src = ((size_t)(b * Ln + R0 + localrow)) * Ln + kc + gd * 8;
            if (w < 8) load_lds16(cosH + src, &Ah[buf][wa * 512]);
            else       load_lds16(cosL + src, &Al[buf][wa * 512]);
        }
        {   // B: wave w -> rows w*8..+8 of the 128-d slice, both planes
            int localrow = w * 8 + (lane >> 3);
            int gd = (lane & 7) ^ (localrow & 7);
            size_t src = ((size_t)(b * Dn + dq * 128 + localrow)) * Ln + kc + gd * 8;
            load_lds16(s2th + src, &Bh[buf][w * 512]);
            load_lds16(s2tl + src, &Bl[buf][w * 512]);
        }
    };

    f32x4 acc[2];
    acc[0] = (f32x4){0.f, 0.f, 0.f, 0.f};
    acc[1] = (f32x4){0.f, 0.f, 0.f, 0.f};

    stage(0, 0);
    __syncthreads();

    for (int kc = 0; kc < Ln; kc += 64) {
        int buf = (kc >> 6) & 1;
        if (kc + 64 < Ln) stage(buf ^ 1, kc + 64);
#pragma unroll
        for (int ks = 0; ks < 64; ks += 32) {
            int kg = (ks >> 3) + lg;
            int rowA = wr * 16 + lr;
            int offA = rowA * 64 + SWZ(rowA, kg) * 8;
            bf16x8 ah = *(const bf16x8*)&Ah[buf][offA];
            bf16x8 al = *(const bf16x8*)&Al[buf][offA];
#pragma unroll
            for (int t = 0; t < 2; ++t) {
                int rowB = wc * 32 + t * 16 + lr;
                int offB = rowB * 64 + SWZ(rowB, kg) * 8;
                bf16x8 bh = *(const bf16x8*)&Bh[buf][offB];
                bf16x8 bl = *(const bf16x8*)&Bl[buf][offB];
                acc[t] = __builtin_amdgcn_mfma_f32_16x16x32_bf16(ah, bh, acc[t], 0, 0, 0);
                acc[t] = __builtin_amdgcn_mfma_f32_16x16x32_bf16(ah, bl, acc[t], 0, 0, 0);
                acc[t] = __builtin_amdgcn_mfma_f32_16x16x32_bf16(al, bh, acc[t], 0, 0, 0);
            }
        }
        __syncthreads();
    }

    // fold ws into ss/sd partials
#pragma unroll
    for (int reg = 0; reg < 4; ++reg) {
        int rloc = wr * 16 + lg * 4 + reg;
        float ssv = 0.f, sdv = 0.f;
#pragma unroll
        for (int t = 0; t < 2; ++t) {
            int dgl = dq * 128 + wc * 32 + t * 16 + lr;
            float wv = acc[t][reg];
            ssv = fmaf(wv, wv, ssv);
            float x = s1b[(size_t)rloc * Dn + dgl];
            sdv = fmaf(x, wv, sdv);
        }
        ssv += __shfl_xor(ssv, 1, 64);
        ssv += __shfl_xor(ssv, 2, 64);
        ssv += __shfl_xor(ssv, 4, 64);
        ssv += __shfl_xor(ssv, 8, 64);
        sdv += __shfl_xor(sdv, 1, 64);
        sdv += __shfl_xor(sdv, 2, 64);
        sdv += __shfl_xor(sdv, 4, 64);
        sdv += __shfl_xor(sdv, 8, 64);
        if (lr == 0) { redS[rloc][wc] = ssv; redD[rloc][wc] = sdv; }
    }
    __syncthreads();
    if (tid < 64) {
        float sS = redS[tid][0] + redS[tid][1] + redS[tid][2] + redS[tid][3];
        float sD = redD[tid][0] + redD[tid][1] + redD[tid][2] + redD[tid][3];
        size_t o = ((size_t)(b * Ln + R0 + tid)) * 8 + dq;
        ssP[o] = sS;
        sdP[o] = sD;
    }
}

// ---------------------------------------------------------------------------
// Kernel 5: epilogue — combine partials + multi-perspective cosine.
// ---------------------------------------------------------------------------
__global__ __launch_bounds__(256) void epi_kernel(
        const float* __restrict__ nrm, const float* __restrict__ kern,
        const float* __restrict__ sumP, const float* __restrict__ ssP,
        const float* __restrict__ sdP, float* __restrict__ out) {
    int idx = blockIdx.x * 256 + threadIdx.x;   // 8192 rows x 16 slots
    int r = idx >> 4, pp = idx & 15;
    if (pp >= Pn) return;
    float ssT = 0.f, sdT = 0.f;
#pragma unroll
    for (int j = 0; j < 8; ++j) { ssT += ssP[r * 8 + j]; sdT += sdP[r * 8 + j]; }
    float scv = sumP[r * 4] + sumP[r * 4 + 1] + sumP[r * 4 + 2] + sumP[r * 4 + 3] + 1e-8f;
    float n1v = nrm[r];
    float kp  = kern[pp];
    float kp2 = kp * kp;
    float wsn = sqrtf(ssT);
    float dot2  = kp2 * sdT / scv;
    float denom = fmaxf(kp2 * n1v * wsn / fabsf(scv), 1e-8f);
    out[(size_t)r * Pn + pp] = dot2 / denom;
}

// ===========================================================================
// Fallback: round-7 fused kernel (proven, 135 us) if ws too small.
// ===========================================================================
__global__ __launch_bounds__(1024, 4) void mfma_fused_kernel(
        const float* __restrict__ s1,
        const float* __restrict__ kern, const float* __restrict__ nrm,
        const short* __restrict__ s2nh, const short* __restrict__ s2nl,
        const short* __restrict__ s2th, const short* __restrict__ s2tl,
        float* __restrict__ out) {
    __shared__ float Sr[32][516];
    __shared__ short Ah[2][32][136];
    __shared__ short Al[2][32][136];
    __shared__ float n2c[Ln];
    __shared__ float n1c[32];
    __shared__ float scl[32];
    __shared__ float red[32][32];
    __shared__ float redS[32][16];
    __shared__ float redD[32][16];
    __shared__ float kc_[16];

    const int tid  = threadIdx.x;
    const int w    = tid >> 6;
    const int lane = tid & 63;
    const int lr   = lane & 15;
    const int lg   = lane >> 4;

    const int wg = ((blockIdx.x & 7) << 5) | (blockIdx.x >> 3);
    const int b  = wg >> 4;
    const int R0 = (wg & 15) * 32;

    const float* s1b = s1 + ((size_t)b * Ln + R0) * Dn;
    const size_t s2row0  = (size_t)b * Ln;
    const size_t s2trow0 = (size_t)b * Dn;

    if (tid < 32) n1c[tid] = nrm[b * Ln + R0 + tid];
    if (tid < Ln) n2c[tid] = nrm[Bn * Ln + b * Ln + tid];
    if (tid < Pn) kc_[tid] = kern[tid];

    auto stageA = [&](int buf, int kb) {
        int r = tid >> 5, k = (tid & 31) * 4;
        float4 v = *(const float4*)(s1b + (size_t)r * Dn + kb + k);
        short2 p0 = bf16split(v.x), p1 = bf16split(v.y),
               p2 = bf16split(v.z), p3 = bf16split(v.w);
        short4 h; h.x = p0.x; h.y = p1.x; h.z = p2.x; h.w = p3.x;
        short4 l; l.x = p0.y; l.y = p1.y; l.z = p2.y; l.w = p3.y;
        *(short4*)&Ah[buf][r][k] = h;
        *(short4*)&Al[buf][r][k] = l;
    };

    f32x4 accA[2][2];
#pragma unroll
    for (int m = 0; m < 2; ++m)
#pragma unroll
        for (int t = 0; t < 2; ++t) accA[m][t] = (f32x4){0.f, 0.f, 0.f, 0.f};

    stageA(0, 0);
    __syncthreads();

    for (int kb = 0; kb < Dn; kb += 128) {
        int cur = (kb >> 7) & 1;
        if (kb + 128 < Dn) stageA(cur ^ 1, kb + 128);
#pragma unroll
        for (int ks = 0; ks < 128; ks += 32) {
            bf16x8 ah[2], al[2];
#pragma unroll
            for (int m = 0; m < 2; ++m) {
                ah[m] = *(const bf16x8*)&Ah[cur][m * 16 + lr][ks + lg * 8];
                al[m] = *(const bf16x8*)&Al[cur][m * 16 + lr][ks + lg * 8];
            }
#pragma unroll
            for (int t = 0; t < 2; ++t) {
                int l2 = (w * 2 + t) * 16 + lr;
                size_t off = (s2row0 + l2) * Dn + kb + ks + lg * 8;
                bf16x8 bh = *(const bf16x8*)(s2nh + off);
                bf16x8 bl = *(const bf16x8*)(s2nl + off);
#pragma unroll
                for (int m = 0; m < 2; ++m) {
                    accA[m][t] = __builtin_amdgcn_mfma_f32_16x16x32_bf16(ah[m], bh, accA[m][t], 0, 0, 0);
                    accA[m][t] = __builtin_amdgcn_mfma_f32_16x16x32_bf16(ah[m], bl, accA[m][t], 0, 0, 0);
                    accA[m][t] = __builtin_amdgcn_mfma_f32_16x16x32_bf16(al[m], bh, accA[m][t], 0, 0, 0);
                }
            }
        }
        __syncthreads();
    }
#pragma unroll
    for (int m = 0; m < 2; ++m)
#pragma unroll
        for (int t = 0; t < 2; ++t)
#pragma unroll
            for (int reg = 0; reg < 4; ++reg)
                Sr[m * 16 + lg * 4 + reg][(w * 2 + t) * 16 + lr] = accA[m][t][reg];
    __syncthreads();

    {
        int r = tid >> 5, part = tid & 31;
        float n1v = n1c[r];
        float s = 0.f;
#pragma unroll 8
        for (int j = 0; j < 16; ++j) {
            int l2 = part + 32 * j;
            float d = Sr[r][l2];
            float cv = d / fmaxf(n1v * n2c[l2], 1e-8f);
            Sr[r][l2] = cv;
            s += cv;
        }
        red[r][part] = s;
    }
    __syncthreads();
    if (tid < 32) {
        float s = 0.f;
#pragma unroll
        for (int j = 0; j < 32; ++j) s += red[tid][j];
        scl[tid] = s + 1e-8f;
    }
    __syncthreads();

    f32x4 accB[2][4];
#pragma unroll
    for (int m = 0; m < 2; ++m)
#pragma unroll
        for (int t = 0; t < 4; ++t) accB[m][t] = (f32x4){0.f, 0.f, 0.f, 0.f};

    for (int kc = 0; kc < Ln; kc += 32) {
        bf16x8 ah[2], al[2];
#pragma unroll
        for (int m = 0; m < 2; ++m) {
            const float* ap = &Sr[m * 16 + lr][kc + lg * 8];
            float4 v0 = *(const float4*)ap;
            float4 v1 = *(const float4*)(ap + 4);
            float f[8] = {v0.x, v0.y, v0.z, v0.w, v1.x, v1.y, v1.z, v1.w};
#pragma unroll
            for (int j = 0; j < 8; ++j) {
                short2 pz = bf16split(f[j]);
                ah[m][j] = pz.x;
                al[m][j] = pz.y;
            }
        }
#pragma unroll
        for (int t = 0; t < 4; ++t) {
            int d = (w * 4 + t) * 16 + lr;
            size_t off = (s2trow0 + d) * Ln + kc + lg * 8;
            bf16x8 bh = *(const bf16x8*)(s2th + off);
            bf16x8 bl = *(const bf16x8*)(s2tl + off);
#pragma unroll
            for (int m = 0; m < 2; ++m) {
                accB[m][t] = __builtin_amdgcn_mfma_f32_16x16x32_bf16(ah[m], bh, accB[m][t], 0, 0, 0);
                accB[m][t] = __builtin_amdgcn_mfma_f32_16x16x32_bf16(ah[m], bl, accB[m][t], 0, 0, 0);
                accB[m][t] = __builtin_amdgcn_mfma_f32_16x16x32_bf16(al[m], bh, accB[m][t], 0, 0, 0);
            }
        }
    }

    float ss[2][4], sd[2][4];
#pragma unroll
    for (int m = 0; m < 2; ++m)
#pragma unroll
        for (int reg = 0; reg < 4; ++reg) { ss[m][reg] = 0.f; sd[m][reg] = 0.f; }

#pragma unroll
    for (int m = 0; m < 2; ++m)
#pragma unroll
        for (int t = 0; t < 4; ++t) {
            int d = (w * 4 + t) * 16 + lr;
#pragma unroll
            for (int reg = 0; reg < 4; ++reg) {
                int row = m * 16 + lg * 4 + reg;
                float wv = accB[m][t][reg];
                ss[m][reg] = fmaf(wv, wv, ss[m][reg]);
                float x = s1b[(size_t)row * Dn + d];
                sd[m][reg] = fmaf(x, wv, sd[m][reg]);
            }
        }
#pragma unroll
    for (int m = 0; m < 2; ++m)
#pragma unroll
        for (int reg = 0; reg < 4; ++reg) {
#pragma unroll
            for (int msk = 8; msk; msk >>= 1) {
                ss[m][reg] += __shfl_xor(ss[m][reg], msk, 64);
                sd[m][reg] += __shfl_xor(sd[m][reg], msk, 64);
            }
        }
    if (lr == 0) {
#pragma unroll
        for (int m = 0; m < 2; ++m)
#pragma unroll
            for (int reg = 0; reg < 4; ++reg) {
                redS[m * 16 + lg * 4 + reg][w] = ss[m][reg];
                redD[m * 16 + lg * 4 + reg][w] = sd[m][reg];
            }
    }
    __syncthreads();

    if (tid < 32 * Pn) {
        int r = tid / Pn, pq = tid % Pn;
        float ssT = 0.f, sdT = 0.f;
#pragma unroll
        for (int j = 0; j < 16; ++j) { ssT += redS[r][j]; sdT += redD[r][j]; }
        float n1v = n1c[r];
        float scv = scl[r];
        float kp  = kc_[pq];
        float kp2 = kp * kp;
        float wsn = sqrtf(ssT);
        float dot2  = kp2 * sdT / scv;
        float denom = fmaxf(kp2 * n1v * wsn / fabsf(scv), 1e-8f);
        out[(size_t)(b * Ln + R0 + r) * Pn + pq] = dot2 / denom;
    }
}

extern "C" void kernel_launch(void* const* d_in, const int* in_sizes, int n_in,
                              void* d_out, int out_size, void* d_ws, size_t ws_size,
                              hipStream_t stream) {
    const float* s1   = (const float*)d_in[0];
    const float* s2   = (const float*)d_in[1];
    const float* kern = (const float*)d_in[2];
    float* out = (float*)d_out;

    char* w = (char*)d_ws;
    float* nrm = (float*)w;                                   // 64 KB
    const size_t SZ1 = (size_t)Bn * Ln * Dn * sizeof(short);  // 16.78 MB
    const size_t SZC = (size_t)Bn * Ln * Ln * sizeof(short);  // 8.39 MB
    short* s2nh = (short*)(w + 65536);
    short* s2nl = (short*)(w + 65536 + SZ1);
    short* s2th = (short*)(w + 65536 + 2 * SZ1);
    short* s2tl = (short*)(w + 65536 + 3 * SZ1);
    short* cosH = (short*)(w + 65536 + 4 * SZ1);
    short* cosL = (short*)(w + 65536 + 4 * SZ1 + SZC);
    float* sumP = (float*)(w + 65536 + 4 * SZ1 + 2 * SZC);    // 128 KB
    // ssP/sdP alias the s2nh plane: s2nh is only read by cos2, which completes
    // before fold2 runs (stream-ordered); prep rewrites s2nh every call.
    float* ssP  = (float*)(w + 65536);                        // 256 KB
    float* sdP  = (float*)(w + 65536 + 262144);               // 256 KB
    const size_t NEED1 = 65536 + 4 * SZ1;                     // ~64.1 MB
    const size_t NEED2 = 65536 + 4 * SZ1 + 2 * SZC + 131072;  // ~84.08 MB (< r9's proven 84.15)

    hipLaunchKernelGGL(norms_kernel, dim3((Bn * Ln * 2) / 4), dim3(256), 0, stream,
                       s1, s2, nrm);

    if (ws_size >= NEED2) {
        hipLaunchKernelGGL(prep_s2_kernel, dim3(Bn * 8 * 16), dim3(256), 0, stream,
                           s2, s2nh, s2nl, s2th, s2tl);
        hipLaunchKernelGGL(cos2_kernel, dim3(512), dim3(1024), 0, stream,
                           s1, nrm, s2nh, s2nl, cosH, cosL, sumP);
        hipLaunchKernelGGL(fold2_kernel, dim3(1024), dim3(1024), 0, stream,
                           s1, s2th, s2tl, cosH, cosL, ssP, sdP);
        hipLaunchKernelGGL(epi_kernel, dim3(Bn * Ln * 16 / 256), dim3(256), 0, stream,
                           nrm, kern, sumP, ssP, sdP, out);
    } else if (ws_size >= NEED1) {
        hipLaunchKernelGGL(prep_s2_kernel, dim3(Bn * 8 * 16), dim3(256), 0, stream,
                           s2, s2nh, s2nl, s2th, s2tl);
        hipLaunchKernelGGL(mfma_fused_kernel, dim3(Bn * (Ln / 32)), dim3(1024), 0, stream,
                           s1, kern, nrm, s2nh, s2nl, s2th, s2tl, out);
    }
}